// Round 1
// baseline (499.114 us; speedup 1.0000x reference)
//
#include <hip/hip_runtime.h>
#include <math.h>

#define NTOT 64000
#define HD   64
#define NB   64
#define FC   512
#define LAT  64
#define OUTD 32
#define GKC  256
#define NKB  250   // 64000 / GKC

// ---------- CSR build ----------
__global__ void k_count(const int* __restrict__ s, const int* __restrict__ r,
                        int* __restrict__ dout, int* __restrict__ din, int nE) {
  int i = blockIdx.x * 256 + threadIdx.x;
  if (i < nE) {
    atomicAdd(&dout[s[i]], 1);
    atomicAdd(&din[r[i]], 1);
  }
}

__global__ void k_scan1(const int* __restrict__ din, int* __restrict__ rs,
                        int* __restrict__ bsums) {
  __shared__ int sm[256];
  int i = blockIdx.x * 256 + threadIdx.x;
  int v = din[i];
  sm[threadIdx.x] = v;
  __syncthreads();
  for (int d = 1; d < 256; d <<= 1) {
    int t = (threadIdx.x >= d) ? sm[threadIdx.x - d] : 0;
    __syncthreads();
    sm[threadIdx.x] += t;
    __syncthreads();
  }
  rs[i] = sm[threadIdx.x] - v;  // local exclusive
  if (threadIdx.x == 255) bsums[blockIdx.x] = sm[255];
}

__global__ void k_scan2(int* __restrict__ rs, int* __restrict__ cur,
                        const int* __restrict__ bsums, int nE) {
  __shared__ int sm[256];
  int bid = blockIdx.x, t = threadIdx.x;
  sm[t] = (t < bid) ? bsums[t] : 0;
  __syncthreads();
  for (int d = 128; d > 0; d >>= 1) {
    if (t < d) sm[t] += sm[t + d];
    __syncthreads();
  }
  int i = bid * 256 + t;
  int v = rs[i] + sm[0];
  rs[i] = v;
  cur[i] = v;
  if (bid == 0 && t == 0) rs[NTOT] = nE;
}

__global__ void k_fill(const int* __restrict__ s, const int* __restrict__ r,
                       int* __restrict__ cur, int* __restrict__ csr, int nE) {
  int i = blockIdx.x * 256 + threadIdx.x;
  if (i < nE) {
    int pos = atomicAdd(&cur[r[i]], 1);
    csr[pos] = s[i];
  }
}

// ---------- encoder node update: h1 = relu(nodes@W1+b1) * rsqrt(deg_out+1) ----------
__global__ __launch_bounds__(256) void k_node1(const float* __restrict__ nodes,
    const float* __restrict__ W1, const float* __restrict__ b1,
    const int* __restrict__ dout, float* __restrict__ h1) {
  __shared__ float wsm[HD * HD];
  int tid = threadIdx.x;
  for (int u = tid; u < HD * HD; u += 256) wsm[u] = W1[u];
  __syncthreads();
  int node = blockIdx.x * 4 + (tid >> 6);
  int f = tid & 63;
  const float* xr = nodes + (size_t)node * HD;
  float acc = b1[f];
#pragma unroll 16
  for (int k = 0; k < HD; k++) acc = fmaf(xr[k], wsm[k * HD + f], acc);
  acc = fmaxf(acc, 0.f);
  h1[(size_t)node * HD + f] = acc * rsqrtf((float)(dout[node] + 1));
}

// ---------- aggregate 1 (with self edge), F=64 ----------
__global__ __launch_bounds__(256) void k_agg1(const float* __restrict__ h1,
    const int* __restrict__ rs, const int* __restrict__ csr,
    const int* __restrict__ din, float* __restrict__ xb) {
  int tid = threadIdx.x;
  int node = blockIdx.x * 4 + (tid >> 6);
  int f = tid & 63;
  int beg = rs[node], end = rs[node + 1];
  float v = h1[(size_t)node * HD + f];  // self edge (already scaled)
  for (int e = beg; e < end; e++) {
    int src = csr[e];
    v += h1[(size_t)src * HD + f];
  }
  xb[(size_t)node * HD + f] = v * rsqrtf((float)(din[node] + 1));
}

// ---------- big GEMM: part[kb] = x[:, k0:k0+GKC] @ Wfc[k0:k0+GKC, :] ----------
__global__ __launch_bounds__(512) void k_gemm(const float* __restrict__ xb,
    const float* __restrict__ Wfc, float* __restrict__ part) {
  __shared__ float xs[64 * GKC];
  int kb = blockIdx.x;
  int k0 = kb * GKC;
  int tid = threadIdx.x;
  for (int u = tid; u < 64 * (GKC / 4); u += 512) {
    int b = u >> 6;       // GKC/4 = 64 quads per row
    int kq = u & 63;
    float4 q = *reinterpret_cast<const float4*>(xb + (size_t)b * 64000 + k0 + kq * 4);
    *reinterpret_cast<float4*>(&xs[b * GKC + kq * 4]) = q;
  }
  __syncthreads();
  int n0 = (tid & 63) * 8;
  int b0 = (tid >> 6) * 8;
  float acc[8][8];
#pragma unroll
  for (int i = 0; i < 8; i++)
#pragma unroll
    for (int j = 0; j < 8; j++) acc[i][j] = 0.f;
  for (int kk = 0; kk < GKC; kk += 4) {
    float4 wv[4][2];
#pragma unroll
    for (int j = 0; j < 4; j++) {
      const float* wr = Wfc + (size_t)(k0 + kk + j) * FC + n0;
      wv[j][0] = *reinterpret_cast<const float4*>(wr);
      wv[j][1] = *reinterpret_cast<const float4*>(wr + 4);
    }
#pragma unroll
    for (int bb = 0; bb < 8; bb++) {
      float4 xq = *reinterpret_cast<const float4*>(&xs[(b0 + bb) * GKC + kk]);
      float xv[4] = {xq.x, xq.y, xq.z, xq.w};
#pragma unroll
      for (int j = 0; j < 4; j++) {
        acc[bb][0] = fmaf(xv[j], wv[j][0].x, acc[bb][0]);
        acc[bb][1] = fmaf(xv[j], wv[j][0].y, acc[bb][1]);
        acc[bb][2] = fmaf(xv[j], wv[j][0].z, acc[bb][2]);
        acc[bb][3] = fmaf(xv[j], wv[j][0].w, acc[bb][3]);
        acc[bb][4] = fmaf(xv[j], wv[j][1].x, acc[bb][4]);
        acc[bb][5] = fmaf(xv[j], wv[j][1].y, acc[bb][5]);
        acc[bb][6] = fmaf(xv[j], wv[j][1].z, acc[bb][6]);
        acc[bb][7] = fmaf(xv[j], wv[j][1].w, acc[bb][7]);
      }
    }
  }
#pragma unroll
  for (int bb = 0; bb < 8; bb++) {
    float4 o0 = make_float4(acc[bb][0], acc[bb][1], acc[bb][2], acc[bb][3]);
    float4 o1 = make_float4(acc[bb][4], acc[bb][5], acc[bb][6], acc[bb][7]);
    float* pr = part + ((size_t)kb * 64 + b0 + bb) * FC + n0;
    *reinterpret_cast<float4*>(pr) = o0;
    *reinterpret_cast<float4*>(pr + 4) = o1;
  }
}

__global__ void k_reduce(const float* __restrict__ part, const float* __restrict__ bfc,
                         float* __restrict__ xf) {
  int i = blockIdx.x * 256 + threadIdx.x;  // < 64*512
  float sv = bfc[i & (FC - 1)];
  for (int kb = 0; kb < NKB; kb++) sv += part[(size_t)kb * (NB * FC) + i];
  xf[i] = fmaxf(sv, 0.f);
}

// ---------- heads + reparameterization ----------
__global__ __launch_bounds__(128) void k_head(const float* __restrict__ xf,
    const float* __restrict__ Wm, const float* __restrict__ bm,
    const float* __restrict__ Wl, const float* __restrict__ bl,
    const float* __restrict__ eps, float* __restrict__ out_mean,
    float* __restrict__ out_logstd, float* __restrict__ z) {
  __shared__ float xr[FC];
  __shared__ float zm[LAT];
  int b = blockIdx.x, t = threadIdx.x;
  for (int u = t; u < FC; u += 128) xr[u] = xf[b * FC + u];
  __syncthreads();
  int l = t & 63;
  const float* W = (t < 64) ? Wm : Wl;
  float acc = (t < 64) ? bm[l] : bl[l];
  for (int k = 0; k < FC; k++) acc = fmaf(xr[k], W[k * LAT + l], acc);
  if (t < 64) {
    out_mean[b * 64 + l] = acc;
    zm[l] = acc;
  }
  __syncthreads();
  if (t >= 64) {
    out_logstd[b * 64 + l] = acc;
    z[b * 64 + l] = zm[l] + expf(acc) * eps[b * 64 + l];
  }
}

// ---------- decoder fc: d = relu(z @ Wdf + bdf), [64][64000] ----------
__global__ __launch_bounds__(256) void k_dec_fc(const float* __restrict__ z,
    const float* __restrict__ Wdf, const float* __restrict__ bdf,
    float* __restrict__ dbuf) {
  __shared__ float zs[NB * LAT];
  int tid = threadIdx.x;
  for (int u = tid; u < NB * LAT; u += 256) zs[u] = z[u];
  __syncthreads();
  int j = blockIdx.x * 32 + (tid & 31);
  int b0 = (tid >> 5) * 8;
  float bias = bdf[j];
  float acc[8];
#pragma unroll
  for (int i = 0; i < 8; i++) acc[i] = bias;
  for (int k = 0; k < LAT; k++) {
    float w = Wdf[(size_t)k * 64000 + j];
#pragma unroll
    for (int i = 0; i < 8; i++) acc[i] = fmaf(zs[(b0 + i) * LAT + k], w, acc[i]);
  }
#pragma unroll
  for (int i = 0; i < 8; i++)
    dbuf[(size_t)(b0 + i) * 64000 + j] = fmaxf(acc[i], 0.f);
}

// ---------- decoder out + pre-scale: dds = (d_r @ Wdo + bdo) * rsqrt(max(deg_out,1)) ----------
__global__ __launch_bounds__(256) void k_dec_out(const float* __restrict__ dbuf,
    const float* __restrict__ Wdo, const float* __restrict__ bdo,
    const int* __restrict__ dout, float* __restrict__ dds) {
  __shared__ float wsm[HD * OUTD];
  __shared__ float dr[8][HD];
  int tid = threadIdx.x;
  for (int u = tid; u < HD * OUTD; u += 256) wsm[u] = Wdo[u];
  int node0 = blockIdx.x * 8;
  {
    int nl = tid >> 5, k = tid & 31;
    dr[nl][k] = dbuf[(size_t)(node0 + nl) * HD + k];
    dr[nl][k + 32] = dbuf[(size_t)(node0 + nl) * HD + k + 32];
  }
  __syncthreads();
  int nl = tid >> 5, f = tid & 31;
  int node = node0 + nl;
  float acc = bdo[f];
#pragma unroll 8
  for (int k = 0; k < HD; k++) acc = fmaf(dr[nl][k], wsm[k * OUTD + f], acc);
  dds[(size_t)node * OUTD + f] = acc * rsqrtf(fmaxf((float)dout[node], 1.f));
}

// ---------- aggregate 2 (no self edges), F=32 ----------
__global__ __launch_bounds__(256) void k_agg2(const float* __restrict__ dds,
    const int* __restrict__ rs, const int* __restrict__ csr,
    const int* __restrict__ din, float* __restrict__ outn) {
  int tid = threadIdx.x;
  int node = blockIdx.x * 4 + (tid >> 6);
  int f = tid & 31;
  int half = (tid >> 5) & 1;
  int beg = rs[node], end = rs[node + 1];
  float v = 0.f;
  for (int e = beg + half; e < end; e += 2) {
    int src = csr[e];
    v += dds[(size_t)src * OUTD + f];
  }
  v += __shfl_xor(v, 32, 64);
  if (half == 0)
    outn[(size_t)node * OUTD + f] = v * rsqrtf(fmaxf((float)din[node], 1.f));
}

extern "C" void kernel_launch(void* const* d_in, const int* in_sizes, int n_in,
                              void* d_out, int out_size, void* d_ws, size_t ws_size,
                              hipStream_t stream) {
  const float* nodes   = (const float*)d_in[0];
  const int*   senders = (const int*)d_in[1];
  const int*   recvs   = (const int*)d_in[2];
  const float* eps     = (const float*)d_in[3];
  const float* W1      = (const float*)d_in[4];
  const float* b1      = (const float*)d_in[5];
  const float* Wfc     = (const float*)d_in[6];
  const float* bfc     = (const float*)d_in[7];
  const float* Wm      = (const float*)d_in[8];
  const float* bm      = (const float*)d_in[9];
  const float* Wl      = (const float*)d_in[10];
  const float* bl      = (const float*)d_in[11];
  const float* Wdf     = (const float*)d_in[12];
  const float* bdf     = (const float*)d_in[13];
  const float* Wdo     = (const float*)d_in[14];
  const float* bdo     = (const float*)d_in[15];
  int nE = in_sizes[1];

  char* w = (char*)d_ws;
  auto alloc = [&](size_t bytes) {
    char* p = w;
    w += (bytes + 255) & ~(size_t)255;
    return p;
  };
  int* deg_out   = (int*)alloc((size_t)NTOT * 4);
  int* deg_in    = (int*)alloc((size_t)NTOT * 4);
  int* row_start = (int*)alloc((size_t)(NTOT + 1) * 4);
  int* cursor    = (int*)alloc((size_t)NTOT * 4);
  int* bsums     = (int*)alloc(256 * 4);
  int* csr       = (int*)alloc((size_t)nE * 4);
  float* h1   = (float*)alloc((size_t)NTOT * HD * 4);
  float* xb   = (float*)alloc((size_t)NTOT * HD * 4);
  float* part = (float*)alloc((size_t)NKB * NB * FC * 4);
  float* xf   = (float*)alloc((size_t)NB * FC * 4);
  float* z    = (float*)alloc((size_t)NB * LAT * 4);
  float* dbuf = h1;   // reuse (h1 dead after k_agg1)
  float* dds  = xb;   // reuse (xb dead after k_gemm)

  float* out_mean   = (float*)d_out;
  float* out_logstd = (float*)d_out + 4096;
  float* out_nodes  = (float*)d_out + 8192;

  int eb = (nE + 255) / 256;
  hipMemsetAsync(deg_out, 0, 2 * (size_t)NTOT * 4, stream);  // deg_out + deg_in adjacent
  k_count<<<eb, 256, 0, stream>>>(senders, recvs, deg_out, deg_in, nE);
  k_scan1<<<NTOT / 256, 256, 0, stream>>>(deg_in, row_start, bsums);
  k_scan2<<<NTOT / 256, 256, 0, stream>>>(row_start, cursor, bsums, nE);
  k_fill<<<eb, 256, 0, stream>>>(senders, recvs, cursor, csr, nE);
  k_node1<<<NTOT / 4, 256, 0, stream>>>(nodes, W1, b1, deg_out, h1);
  k_agg1<<<NTOT / 4, 256, 0, stream>>>(h1, row_start, csr, deg_in, xb);
  k_gemm<<<NKB, 512, 0, stream>>>(xb, Wfc, part);
  k_reduce<<<NB * FC / 256, 256, 0, stream>>>(part, bfc, xf);
  k_head<<<NB, 128, 0, stream>>>(xf, Wm, bm, Wl, bl, eps, out_mean, out_logstd, z);
  k_dec_fc<<<64000 / 32, 256, 0, stream>>>(z, Wdf, bdf, dbuf);
  k_dec_out<<<NTOT / 8, 256, 0, stream>>>(dbuf, Wdo, bdo, deg_out, dds);
  k_agg2<<<NTOT / 4, 256, 0, stream>>>(dds, row_start, csr, deg_in, out_nodes);
}

// Round 2
// 408.412 us; speedup vs baseline: 1.2221x; 1.2221x over previous
//
#include <hip/hip_runtime.h>
#include <math.h>

#define NTOT 64000
#define HD   64
#define NB   64
#define FC   512
#define LAT  64
#define OUTD 32
#define GKC  256
#define NKB  250   // 64000 / GKC

// ---------- CSR build ----------
__global__ void k_count(const int* __restrict__ s, const int* __restrict__ r,
                        int* __restrict__ dout, int* __restrict__ din, int nE) {
  int i = blockIdx.x * 256 + threadIdx.x;
  if (i < nE) {
    atomicAdd(&dout[s[i]], 1);
    atomicAdd(&din[r[i]], 1);
  }
}

__global__ void k_scan1(const int* __restrict__ din, int* __restrict__ rs,
                        int* __restrict__ bsums) {
  __shared__ int sm[256];
  int i = blockIdx.x * 256 + threadIdx.x;
  int v = din[i];
  sm[threadIdx.x] = v;
  __syncthreads();
  for (int d = 1; d < 256; d <<= 1) {
    int t = (threadIdx.x >= d) ? sm[threadIdx.x - d] : 0;
    __syncthreads();
    sm[threadIdx.x] += t;
    __syncthreads();
  }
  rs[i] = sm[threadIdx.x] - v;  // local exclusive
  if (threadIdx.x == 255) bsums[blockIdx.x] = sm[255];
}

__global__ void k_scan2(int* __restrict__ rs, int* __restrict__ cur,
                        const int* __restrict__ bsums, int nE) {
  __shared__ int sm[256];
  int bid = blockIdx.x, t = threadIdx.x;
  sm[t] = (t < bid) ? bsums[t] : 0;
  __syncthreads();
  for (int d = 128; d > 0; d >>= 1) {
    if (t < d) sm[t] += sm[t + d];
    __syncthreads();
  }
  int i = bid * 256 + t;
  int v = rs[i] + sm[0];
  rs[i] = v;
  cur[i] = v;
  if (bid == 0 && t == 0) rs[NTOT] = nE;
}

__global__ void k_fill(const int* __restrict__ s, const int* __restrict__ r,
                       int* __restrict__ cur, int* __restrict__ csr, int nE) {
  int i = blockIdx.x * 256 + threadIdx.x;
  if (i < nE) {
    int pos = atomicAdd(&cur[r[i]], 1);
    csr[pos] = s[i];
  }
}

// ---------- encoder node update: h1 = relu(nodes@W1+b1) * rsqrt(deg_out+1) ----------
__global__ __launch_bounds__(256) void k_node1(const float* __restrict__ nodes,
    const float* __restrict__ W1, const float* __restrict__ b1,
    const int* __restrict__ dout, float* __restrict__ h1) {
  __shared__ float wsm[HD * HD];
  int tid = threadIdx.x;
  for (int u = tid; u < HD * HD; u += 256) wsm[u] = W1[u];
  __syncthreads();
  int node = blockIdx.x * 4 + (tid >> 6);
  int f = tid & 63;
  const float* xr = nodes + (size_t)node * HD;
  float acc = b1[f];
#pragma unroll 16
  for (int k = 0; k < HD; k++) acc = fmaf(xr[k], wsm[k * HD + f], acc);
  acc = fmaxf(acc, 0.f);
  h1[(size_t)node * HD + f] = acc * rsqrtf((float)(dout[node] + 1));
}

// ---------- aggregate 1 (with self edge), F=64, 4-way MLP unroll ----------
__global__ __launch_bounds__(256) void k_agg1(const float* __restrict__ h1,
    const int* __restrict__ rs, const int* __restrict__ csr,
    const int* __restrict__ din, float* __restrict__ xb) {
  int tid = threadIdx.x;
  int node = blockIdx.x * 4 + (tid >> 6);
  int f = tid & 63;
  int beg = rs[node], end = rs[node + 1];
  float v0 = h1[(size_t)node * HD + f];  // self edge (already scaled)
  float v1 = 0.f, v2 = 0.f, v3 = 0.f;
  int e = beg;
  for (; e + 4 <= end; e += 4) {
    int s0 = csr[e], s1 = csr[e + 1], s2 = csr[e + 2], s3 = csr[e + 3];
    v0 += h1[(size_t)s0 * HD + f];
    v1 += h1[(size_t)s1 * HD + f];
    v2 += h1[(size_t)s2 * HD + f];
    v3 += h1[(size_t)s3 * HD + f];
  }
  for (; e < end; e++) v1 += h1[(size_t)csr[e] * HD + f];
  float v = (v0 + v1) + (v2 + v3);
  xb[(size_t)node * HD + f] = v * rsqrtf((float)(din[node] + 1));
}

// ---------- big GEMM: part[kb] = x[:, k0:k0+GKC] @ Wfc[k0:k0+GKC, :] ----------
// 1024 threads: thread tile 8b x 4n, W-prefetch double buffer.
__global__ __launch_bounds__(1024) void k_gemm(const float* __restrict__ xb,
    const float* __restrict__ Wfc, float* __restrict__ part) {
  __shared__ float xs[64 * GKC];  // 64 KB
  int kb = blockIdx.x;
  int k0 = kb * GKC;
  int tid = threadIdx.x;
  for (int u = tid; u < 64 * (GKC / 4); u += 1024) {
    int b = u >> 6;
    int kq = u & 63;
    float4 q = *reinterpret_cast<const float4*>(xb + (size_t)b * 64000 + k0 + kq * 4);
    *reinterpret_cast<float4*>(&xs[b * GKC + kq * 4]) = q;
  }
  __syncthreads();
  int n0 = (tid & 127) * 4;
  int b0 = (tid >> 7) * 8;
  float acc[8][4];
#pragma unroll
  for (int i = 0; i < 8; i++)
#pragma unroll
    for (int j = 0; j < 4; j++) acc[i][j] = 0.f;

  float4 wv[4], wn[4];
#pragma unroll
  for (int j = 0; j < 4; j++)
    wv[j] = *reinterpret_cast<const float4*>(Wfc + (size_t)(k0 + j) * FC + n0);

  for (int kk = 0; kk < GKC; kk += 4) {
    int kn = (kk + 4 < GKC) ? kk + 4 : kk;  // last iter: harmless reload
#pragma unroll
    for (int j = 0; j < 4; j++)
      wn[j] = *reinterpret_cast<const float4*>(Wfc + (size_t)(k0 + kn + j) * FC + n0);
#pragma unroll
    for (int bb = 0; bb < 8; bb++) {
      float4 xq = *reinterpret_cast<const float4*>(&xs[(b0 + bb) * GKC + kk]);
      acc[bb][0] = fmaf(xq.x, wv[0].x, acc[bb][0]);
      acc[bb][1] = fmaf(xq.x, wv[0].y, acc[bb][1]);
      acc[bb][2] = fmaf(xq.x, wv[0].z, acc[bb][2]);
      acc[bb][3] = fmaf(xq.x, wv[0].w, acc[bb][3]);
      acc[bb][0] = fmaf(xq.y, wv[1].x, acc[bb][0]);
      acc[bb][1] = fmaf(xq.y, wv[1].y, acc[bb][1]);
      acc[bb][2] = fmaf(xq.y, wv[1].z, acc[bb][2]);
      acc[bb][3] = fmaf(xq.y, wv[1].w, acc[bb][3]);
      acc[bb][0] = fmaf(xq.z, wv[2].x, acc[bb][0]);
      acc[bb][1] = fmaf(xq.z, wv[2].y, acc[bb][1]);
      acc[bb][2] = fmaf(xq.z, wv[2].z, acc[bb][2]);
      acc[bb][3] = fmaf(xq.z, wv[2].w, acc[bb][3]);
      acc[bb][0] = fmaf(xq.w, wv[3].x, acc[bb][0]);
      acc[bb][1] = fmaf(xq.w, wv[3].y, acc[bb][1]);
      acc[bb][2] = fmaf(xq.w, wv[3].z, acc[bb][2]);
      acc[bb][3] = fmaf(xq.w, wv[3].w, acc[bb][3]);
    }
#pragma unroll
    for (int j = 0; j < 4; j++) wv[j] = wn[j];
  }
#pragma unroll
  for (int bb = 0; bb < 8; bb++) {
    float4 o = make_float4(acc[bb][0], acc[bb][1], acc[bb][2], acc[bb][3]);
    *reinterpret_cast<float4*>(part + ((size_t)kb * 64 + b0 + bb) * FC + n0) = o;
  }
}

// ---------- reduce partials: xf = relu(sum_kb part + bfc) ----------
__global__ __launch_bounds__(256) void k_reduce(const float* __restrict__ part,
    const float* __restrict__ bfc, float* __restrict__ xf) {
  __shared__ float sm[256];
  int t = threadIdx.x;
  int i = blockIdx.x * 128 + (t & 127);  // output index < 32768
  int half = t >> 7;
  float sv = 0.f;
  int kb0 = half * (NKB / 2);
  int kb1 = kb0 + (NKB / 2);
  for (int kb = kb0; kb < kb1; kb++) sv += part[(size_t)kb * (NB * FC) + i];
  sm[t] = sv;
  __syncthreads();
  if (half == 0)
    xf[i] = fmaxf(sm[t] + sm[t + 128] + bfc[i & (FC - 1)], 0.f);
}

// ---------- heads + reparameterization (256 thr: 2 heads x 2 K-halves) ----------
__global__ __launch_bounds__(256) void k_head(const float* __restrict__ xf,
    const float* __restrict__ Wm, const float* __restrict__ bm,
    const float* __restrict__ Wl, const float* __restrict__ bl,
    const float* __restrict__ eps, float* __restrict__ out_mean,
    float* __restrict__ out_logstd, float* __restrict__ z) {
  __shared__ float xr[FC];
  __shared__ float ps[4][LAT];
  __shared__ float zm[LAT];
  int b = blockIdx.x, t = threadIdx.x;
  for (int u = t; u < FC; u += 256) xr[u] = xf[b * FC + u];
  __syncthreads();
  int g = t >> 6;      // 0: mean k-lo, 1: mean k-hi, 2: ls k-lo, 3: ls k-hi
  int l = t & 63;
  int h = g & 1;
  const float* W = (g < 2) ? Wm : Wl;
  float acc = 0.f;
  int kb = h * (FC / 2);
#pragma unroll 8
  for (int k = kb; k < kb + FC / 2; k++) acc = fmaf(xr[k], W[k * LAT + l], acc);
  ps[g][l] = acc;
  __syncthreads();
  float ls = 0.f;
  if (g == 0) {
    float m = ps[0][l] + ps[1][l] + bm[l];
    out_mean[b * 64 + l] = m;
    zm[l] = m;
  }
  if (g == 2) {
    ls = ps[2][l] + ps[3][l] + bl[l];
    out_logstd[b * 64 + l] = ls;
  }
  __syncthreads();
  if (g == 2) z[b * 64 + l] = zm[l] + expf(ls) * eps[b * 64 + l];
}

// ---------- decoder fc: d = relu(z @ Wdf + bdf), [64][64000] ----------
__global__ __launch_bounds__(256) void k_dec_fc(const float* __restrict__ z,
    const float* __restrict__ Wdf, const float* __restrict__ bdf,
    float* __restrict__ dbuf) {
  __shared__ float zs[NB * LAT];
  int tid = threadIdx.x;
  for (int u = tid; u < NB * LAT; u += 256) zs[u] = z[u];
  __syncthreads();
  int j = blockIdx.x * 32 + (tid & 31);
  int b0 = (tid >> 5) * 8;
  float bias = bdf[j];
  float acc[8];
#pragma unroll
  for (int i = 0; i < 8; i++) acc[i] = bias;
  for (int k = 0; k < LAT; k++) {
    float w = Wdf[(size_t)k * 64000 + j];
#pragma unroll
    for (int i = 0; i < 8; i++) acc[i] = fmaf(zs[(b0 + i) * LAT + k], w, acc[i]);
  }
#pragma unroll
  for (int i = 0; i < 8; i++)
    dbuf[(size_t)(b0 + i) * 64000 + j] = fmaxf(acc[i], 0.f);
}

// ---------- decoder out + pre-scale: dds = (d_r @ Wdo + bdo) * rsqrt(max(deg_out,1)) ----------
__global__ __launch_bounds__(256) void k_dec_out(const float* __restrict__ dbuf,
    const float* __restrict__ Wdo, const float* __restrict__ bdo,
    const int* __restrict__ dout, float* __restrict__ dds) {
  __shared__ float wsm[HD * OUTD];
  __shared__ float dr[8][HD];
  int tid = threadIdx.x;
  for (int u = tid; u < HD * OUTD; u += 256) wsm[u] = Wdo[u];
  int node0 = blockIdx.x * 8;
  {
    int nl = tid >> 5, k = tid & 31;
    dr[nl][k] = dbuf[(size_t)(node0 + nl) * HD + k];
    dr[nl][k + 32] = dbuf[(size_t)(node0 + nl) * HD + k + 32];
  }
  __syncthreads();
  int nl = tid >> 5, f = tid & 31;
  int node = node0 + nl;
  float acc = bdo[f];
#pragma unroll 8
  for (int k = 0; k < HD; k++) acc = fmaf(dr[nl][k], wsm[k * OUTD + f], acc);
  dds[(size_t)node * OUTD + f] = acc * rsqrtf(fmaxf((float)dout[node], 1.f));
}

// ---------- aggregate 2 (no self edges), F=32, 4-way MLP unroll ----------
__global__ __launch_bounds__(256) void k_agg2(const float* __restrict__ dds,
    const int* __restrict__ rs, const int* __restrict__ csr,
    const int* __restrict__ din, float* __restrict__ outn) {
  int tid = threadIdx.x;
  int node = blockIdx.x * 8 + (tid >> 5);
  int f = tid & 31;
  int beg = rs[node], end = rs[node + 1];
  float v0 = 0.f, v1 = 0.f, v2 = 0.f, v3 = 0.f;
  int e = beg;
  for (; e + 4 <= end; e += 4) {
    int s0 = csr[e], s1 = csr[e + 1], s2 = csr[e + 2], s3 = csr[e + 3];
    v0 += dds[(size_t)s0 * OUTD + f];
    v1 += dds[(size_t)s1 * OUTD + f];
    v2 += dds[(size_t)s2 * OUTD + f];
    v3 += dds[(size_t)s3 * OUTD + f];
  }
  for (; e < end; e++) v1 += dds[(size_t)csr[e] * OUTD + f];
  float v = (v0 + v1) + (v2 + v3);
  outn[(size_t)node * OUTD + f] = v * rsqrtf(fmaxf((float)din[node], 1.f));
}

extern "C" void kernel_launch(void* const* d_in, const int* in_sizes, int n_in,
                              void* d_out, int out_size, void* d_ws, size_t ws_size,
                              hipStream_t stream) {
  const float* nodes   = (const float*)d_in[0];
  const int*   senders = (const int*)d_in[1];
  const int*   recvs   = (const int*)d_in[2];
  const float* eps     = (const float*)d_in[3];
  const float* W1      = (const float*)d_in[4];
  const float* b1      = (const float*)d_in[5];
  const float* Wfc     = (const float*)d_in[6];
  const float* bfc     = (const float*)d_in[7];
  const float* Wm      = (const float*)d_in[8];
  const float* bm      = (const float*)d_in[9];
  const float* Wl      = (const float*)d_in[10];
  const float* bl      = (const float*)d_in[11];
  const float* Wdf     = (const float*)d_in[12];
  const float* bdf     = (const float*)d_in[13];
  const float* Wdo     = (const float*)d_in[14];
  const float* bdo     = (const float*)d_in[15];
  int nE = in_sizes[1];

  char* w = (char*)d_ws;
  auto alloc = [&](size_t bytes) {
    char* p = w;
    w += (bytes + 255) & ~(size_t)255;
    return p;
  };
  int* deg_out   = (int*)alloc((size_t)NTOT * 4);
  int* deg_in    = (int*)alloc((size_t)NTOT * 4);
  int* row_start = (int*)alloc((size_t)(NTOT + 1) * 4);
  int* cursor    = (int*)alloc((size_t)NTOT * 4);
  int* bsums     = (int*)alloc(256 * 4);
  int* csr       = (int*)alloc((size_t)nE * 4);
  float* h1   = (float*)alloc((size_t)NTOT * HD * 4);
  float* xb   = (float*)alloc((size_t)NTOT * HD * 4);
  float* part = (float*)alloc((size_t)NKB * NB * FC * 4);
  float* xf   = (float*)alloc((size_t)NB * FC * 4);
  float* z    = (float*)alloc((size_t)NB * LAT * 4);
  float* dbuf = h1;   // reuse (h1 dead after k_agg1)
  float* dds  = xb;   // reuse (xb dead after k_gemm)

  float* out_mean   = (float*)d_out;
  float* out_logstd = (float*)d_out + 4096;
  float* out_nodes  = (float*)d_out + 8192;

  int eb = (nE + 255) / 256;
  hipMemsetAsync(deg_out, 0, 2 * (size_t)NTOT * 4, stream);  // deg_out + deg_in adjacent
  k_count<<<eb, 256, 0, stream>>>(senders, recvs, deg_out, deg_in, nE);
  k_scan1<<<NTOT / 256, 256, 0, stream>>>(deg_in, row_start, bsums);
  k_scan2<<<NTOT / 256, 256, 0, stream>>>(row_start, cursor, bsums, nE);
  k_fill<<<eb, 256, 0, stream>>>(senders, recvs, cursor, csr, nE);
  k_node1<<<NTOT / 4, 256, 0, stream>>>(nodes, W1, b1, deg_out, h1);
  k_agg1<<<NTOT / 4, 256, 0, stream>>>(h1, row_start, csr, deg_in, xb);
  k_gemm<<<NKB, 1024, 0, stream>>>(xb, Wfc, part);
  k_reduce<<<NB * FC / 128, 256, 0, stream>>>(part, bfc, xf);
  k_head<<<NB, 256, 0, stream>>>(xf, Wm, bm, Wl, bl, eps, out_mean, out_logstd, z);
  k_dec_fc<<<64000 / 32, 256, 0, stream>>>(z, Wdf, bdf, dbuf);
  k_dec_out<<<NTOT / 8, 256, 0, stream>>>(dbuf, Wdo, bdo, deg_out, dds);
  k_agg2<<<NTOT / 8, 256, 0, stream>>>(dds, row_start, csr, deg_in, out_nodes);
}

// Round 3
// 362.819 us; speedup vs baseline: 1.3757x; 1.1257x over previous
//
#include <hip/hip_runtime.h>
#include <math.h>

#define NTOT 64000
#define HD   64
#define NB   64
#define FC   512
#define LAT  64
#define OUTD 32
#define GKC  256
#define NKB  250   // 64000 / GKC

typedef __bf16 bf16x8 __attribute__((ext_vector_type(8)));
typedef float  f32x4  __attribute__((ext_vector_type(4)));

// ---------- CSR build ----------
__global__ void k_count(const int* __restrict__ s, const int* __restrict__ r,
                        int* __restrict__ dout, int* __restrict__ din, int nE) {
  int i = blockIdx.x * 256 + threadIdx.x;
  if (i < nE) {
    atomicAdd(&dout[s[i]], 1);
    atomicAdd(&din[r[i]], 1);
  }
}

__global__ void k_scan1(const int* __restrict__ din, int* __restrict__ rs,
                        int* __restrict__ bsums) {
  __shared__ int sm[256];
  int i = blockIdx.x * 256 + threadIdx.x;
  int v = din[i];
  sm[threadIdx.x] = v;
  __syncthreads();
  for (int d = 1; d < 256; d <<= 1) {
    int t = (threadIdx.x >= d) ? sm[threadIdx.x - d] : 0;
    __syncthreads();
    sm[threadIdx.x] += t;
    __syncthreads();
  }
  rs[i] = sm[threadIdx.x] - v;  // local exclusive
  if (threadIdx.x == 255) bsums[blockIdx.x] = sm[255];
}

__global__ void k_scan2(int* __restrict__ rs, int* __restrict__ cur,
                        const int* __restrict__ bsums, int nE) {
  __shared__ int sm[256];
  int bid = blockIdx.x, t = threadIdx.x;
  sm[t] = (t < bid) ? bsums[t] : 0;
  __syncthreads();
  for (int d = 128; d > 0; d >>= 1) {
    if (t < d) sm[t] += sm[t + d];
    __syncthreads();
  }
  int i = bid * 256 + t;
  int v = rs[i] + sm[0];
  rs[i] = v;
  cur[i] = v;
  if (bid == 0 && t == 0) rs[NTOT] = nE;
}

__global__ void k_fill(const int* __restrict__ s, const int* __restrict__ r,
                       int* __restrict__ cur, int* __restrict__ csr, int nE) {
  int i = blockIdx.x * 256 + threadIdx.x;
  if (i < nE) {
    int pos = atomicAdd(&cur[r[i]], 1);
    csr[pos] = s[i];
  }
}

// ---------- encoder node update: h1 = relu(nodes@W1+b1) * rsqrt(deg_out+1), bf16 out ----------
__global__ __launch_bounds__(256) void k_node1(const float* __restrict__ nodes,
    const float* __restrict__ W1, const float* __restrict__ b1,
    const int* __restrict__ dout, __bf16* __restrict__ h1) {
  __shared__ float wsm[HD * HD];
  int tid = threadIdx.x;
  for (int u = tid; u < HD * HD; u += 256) wsm[u] = W1[u];
  __syncthreads();
  int node = blockIdx.x * 4 + (tid >> 6);
  int f = tid & 63;
  const float* xr = nodes + (size_t)node * HD;
  float acc = b1[f];
#pragma unroll 16
  for (int k = 0; k < HD; k++) acc = fmaf(xr[k], wsm[k * HD + f], acc);
  acc = fmaxf(acc, 0.f);
  h1[(size_t)node * HD + f] = (__bf16)(acc * rsqrtf((float)(dout[node] + 1)));
}

// ---------- aggregate 1 (with self edge), F=64, bf16 in/out ----------
__global__ __launch_bounds__(256) void k_agg1(const __bf16* __restrict__ h1,
    const int* __restrict__ rs, const int* __restrict__ csr,
    const int* __restrict__ din, __bf16* __restrict__ xbo) {
  int tid = threadIdx.x;
  int node = blockIdx.x * 4 + (tid >> 6);
  int f = tid & 63;
  int beg = rs[node], end = rs[node + 1];
  float v0 = (float)h1[(size_t)node * HD + f];  // self edge (already scaled)
  float v1 = 0.f, v2 = 0.f, v3 = 0.f;
  int e = beg;
  for (; e + 4 <= end; e += 4) {
    int s0 = csr[e], s1 = csr[e + 1], s2 = csr[e + 2], s3 = csr[e + 3];
    v0 += (float)h1[(size_t)s0 * HD + f];
    v1 += (float)h1[(size_t)s1 * HD + f];
    v2 += (float)h1[(size_t)s2 * HD + f];
    v3 += (float)h1[(size_t)s3 * HD + f];
  }
  for (; e < end; e++) v1 += (float)h1[(size_t)csr[e] * HD + f];
  float v = (v0 + v1) + (v2 + v3);
  xbo[(size_t)node * HD + f] = (__bf16)(v * rsqrtf((float)(din[node] + 1)));
}

// ---------- big GEMM (MFMA bf16): part[kb] = x[:, k0:+256] @ Wfc[k0:+256, :] ----------
// 512 thr = 8 waves; wave w owns cols [w*64, w*64+64). A in LDS (bf16, +8 pad).
// B read fp32 -> cvt bf16 in regs (no redundancy: wave-owned N slice).
__global__ __launch_bounds__(512) void k_gemm(const __bf16* __restrict__ xb,
    const float* __restrict__ Wfc, float* __restrict__ part) {
  __shared__ __align__(16) __bf16 As[64 * 264];  // 33 KB, row pad +8
  int kb = blockIdx.x;
  int k0 = kb * GKC;
  int tid = threadIdx.x;
  // stage A: 64 rows x 256 bf16 (32 uint4 per row)
  for (int u = tid; u < 64 * 32; u += 512) {
    int row = u >> 5, c = u & 31;
    const uint4* src = reinterpret_cast<const uint4*>(xb + (size_t)row * 64000 + k0);
    reinterpret_cast<uint4*>(&As[row * 264])[c] = src[c];
  }
  __syncthreads();
  int w = tid >> 6, lane = tid & 63;
  int cw = lane & 15, kg = lane >> 4;
  const float* Bp = Wfc + ((size_t)k0 + kg * 8) * FC + w * 64 + cw;
  f32x4 acc[4][4];
#pragma unroll
  for (int mt = 0; mt < 4; mt++)
#pragma unroll
    for (int nt = 0; nt < 4; nt++) acc[mt][nt] = (f32x4){0.f, 0.f, 0.f, 0.f};

  for (int ks = 0; ks < 8; ks++) {
    bf16x8 bfrag[4];
#pragma unroll
    for (int nt = 0; nt < 4; nt++) {
      const float* bp = Bp + (size_t)ks * 32 * FC + nt * 16;
      bf16x8 bb;
#pragma unroll
      for (int b = 0; b < 8; b++) bb[b] = (__bf16)bp[(size_t)b * FC];
      bfrag[nt] = bb;
    }
    bf16x8 afrag[4];
#pragma unroll
    for (int mt = 0; mt < 4; mt++)
      afrag[mt] = *reinterpret_cast<const bf16x8*>(
          &As[(mt * 16 + cw) * 264 + ks * 32 + kg * 8]);
#pragma unroll
    for (int mt = 0; mt < 4; mt++)
#pragma unroll
      for (int nt = 0; nt < 4; nt++)
        acc[mt][nt] = __builtin_amdgcn_mfma_f32_16x16x32_bf16(
            afrag[mt], bfrag[nt], acc[mt][nt], 0, 0, 0);
  }
  // C write: row = mt*16 + kg*4 + j, col = w*64 + nt*16 + cw
#pragma unroll
  for (int mt = 0; mt < 4; mt++)
#pragma unroll
    for (int nt = 0; nt < 4; nt++) {
      int col = w * 64 + nt * 16 + cw;
#pragma unroll
      for (int j = 0; j < 4; j++) {
        int row = mt * 16 + kg * 4 + j;
        part[((size_t)kb * 64 + row) * FC + col] = acc[mt][nt][j];
      }
    }
}

// ---------- reduce partials: xf = relu(sum_kb part + bfc) ----------
__global__ __launch_bounds__(256) void k_reduce(const float* __restrict__ part,
    const float* __restrict__ bfc, float* __restrict__ xf) {
  __shared__ float sm[256];
  int t = threadIdx.x;
  int i = blockIdx.x * 128 + (t & 127);  // output index < 32768
  int half = t >> 7;
  float sv = 0.f;
  int kb0 = half * (NKB / 2);
  int kb1 = kb0 + (NKB / 2);
  for (int kb = kb0; kb < kb1; kb++) sv += part[(size_t)kb * (NB * FC) + i];
  sm[t] = sv;
  __syncthreads();
  if (half == 0)
    xf[i] = fmaxf(sm[t] + sm[t + 128] + bfc[i & (FC - 1)], 0.f);
}

// ---------- heads + reparameterization (256 thr: 2 heads x 2 K-halves) ----------
__global__ __launch_bounds__(256) void k_head(const float* __restrict__ xf,
    const float* __restrict__ Wm, const float* __restrict__ bm,
    const float* __restrict__ Wl, const float* __restrict__ bl,
    const float* __restrict__ eps, float* __restrict__ out_mean,
    float* __restrict__ out_logstd, float* __restrict__ z) {
  __shared__ float xr[FC];
  __shared__ float ps[4][LAT];
  __shared__ float zm[LAT];
  int b = blockIdx.x, t = threadIdx.x;
  for (int u = t; u < FC; u += 256) xr[u] = xf[b * FC + u];
  __syncthreads();
  int g = t >> 6;      // 0: mean k-lo, 1: mean k-hi, 2: ls k-lo, 3: ls k-hi
  int l = t & 63;
  int h = g & 1;
  const float* W = (g < 2) ? Wm : Wl;
  float acc = 0.f;
  int kb = h * (FC / 2);
#pragma unroll 8
  for (int k = kb; k < kb + FC / 2; k++) acc = fmaf(xr[k], W[k * LAT + l], acc);
  ps[g][l] = acc;
  __syncthreads();
  float ls = 0.f;
  if (g == 0) {
    float m = ps[0][l] + ps[1][l] + bm[l];
    out_mean[b * 64 + l] = m;
    zm[l] = m;
  }
  if (g == 2) {
    ls = ps[2][l] + ps[3][l] + bl[l];
    out_logstd[b * 64 + l] = ls;
  }
  __syncthreads();
  if (g == 2) z[b * 64 + l] = zm[l] + expf(ls) * eps[b * 64 + l];
}

// ---------- decoder fc: d = relu(z @ Wdf + bdf), bf16 out ----------
__global__ __launch_bounds__(256) void k_dec_fc(const float* __restrict__ z,
    const float* __restrict__ Wdf, const float* __restrict__ bdf,
    __bf16* __restrict__ dbuf) {
  __shared__ float zs[NB * LAT];
  int tid = threadIdx.x;
  for (int u = tid; u < NB * LAT; u += 256) zs[u] = z[u];
  __syncthreads();
  int j = blockIdx.x * 32 + (tid & 31);
  int b0 = (tid >> 5) * 8;
  float bias = bdf[j];
  float acc[8];
#pragma unroll
  for (int i = 0; i < 8; i++) acc[i] = bias;
  for (int k = 0; k < LAT; k++) {
    float w = Wdf[(size_t)k * 64000 + j];
#pragma unroll
    for (int i = 0; i < 8; i++) acc[i] = fmaf(zs[(b0 + i) * LAT + k], w, acc[i]);
  }
#pragma unroll
  for (int i = 0; i < 8; i++)
    dbuf[(size_t)(b0 + i) * 64000 + j] = (__bf16)fmaxf(acc[i], 0.f);
}

// ---------- decoder out + pre-scale: dds = (d_r @ Wdo + bdo) * rsqrt(max(deg_out,1)), bf16 ----------
__global__ __launch_bounds__(256) void k_dec_out(const __bf16* __restrict__ dbuf,
    const float* __restrict__ Wdo, const float* __restrict__ bdo,
    const int* __restrict__ dout, __bf16* __restrict__ dds) {
  __shared__ float wsm[HD * OUTD];
  __shared__ float dr[8][HD];
  int tid = threadIdx.x;
  for (int u = tid; u < HD * OUTD; u += 256) wsm[u] = Wdo[u];
  int node0 = blockIdx.x * 8;
  {
    int nl = tid >> 5, k = tid & 31;
    dr[nl][k]      = (float)dbuf[(size_t)(node0 + nl) * HD + k];
    dr[nl][k + 32] = (float)dbuf[(size_t)(node0 + nl) * HD + k + 32];
  }
  __syncthreads();
  int nl = tid >> 5, f = tid & 31;
  int node = node0 + nl;
  float acc = bdo[f];
#pragma unroll 8
  for (int k = 0; k < HD; k++) acc = fmaf(dr[nl][k], wsm[k * OUTD + f], acc);
  dds[(size_t)node * OUTD + f] = (__bf16)(acc * rsqrtf(fmaxf((float)dout[node], 1.f)));
}

// ---------- aggregate 2 (no self edges), F=32, bf16 gather ----------
__global__ __launch_bounds__(256) void k_agg2(const __bf16* __restrict__ dds,
    const int* __restrict__ rs, const int* __restrict__ csr,
    const int* __restrict__ din, float* __restrict__ outn) {
  int tid = threadIdx.x;
  int node = blockIdx.x * 8 + (tid >> 5);
  int f = tid & 31;
  int beg = rs[node], end = rs[node + 1];
  float v0 = 0.f, v1 = 0.f, v2 = 0.f, v3 = 0.f;
  int e = beg;
  for (; e + 4 <= end; e += 4) {
    int s0 = csr[e], s1 = csr[e + 1], s2 = csr[e + 2], s3 = csr[e + 3];
    v0 += (float)dds[(size_t)s0 * OUTD + f];
    v1 += (float)dds[(size_t)s1 * OUTD + f];
    v2 += (float)dds[(size_t)s2 * OUTD + f];
    v3 += (float)dds[(size_t)s3 * OUTD + f];
  }
  for (; e < end; e++) v1 += (float)dds[(size_t)csr[e] * OUTD + f];
  float v = (v0 + v1) + (v2 + v3);
  outn[(size_t)node * OUTD + f] = v * rsqrtf(fmaxf((float)din[node], 1.f));
}

extern "C" void kernel_launch(void* const* d_in, const int* in_sizes, int n_in,
                              void* d_out, int out_size, void* d_ws, size_t ws_size,
                              hipStream_t stream) {
  const float* nodes   = (const float*)d_in[0];
  const int*   senders = (const int*)d_in[1];
  const int*   recvs   = (const int*)d_in[2];
  const float* eps     = (const float*)d_in[3];
  const float* W1      = (const float*)d_in[4];
  const float* b1      = (const float*)d_in[5];
  const float* Wfc     = (const float*)d_in[6];
  const float* bfc     = (const float*)d_in[7];
  const float* Wm      = (const float*)d_in[8];
  const float* bm      = (const float*)d_in[9];
  const float* Wl      = (const float*)d_in[10];
  const float* bl      = (const float*)d_in[11];
  const float* Wdf     = (const float*)d_in[12];
  const float* bdf     = (const float*)d_in[13];
  const float* Wdo     = (const float*)d_in[14];
  const float* bdo     = (const float*)d_in[15];
  int nE = in_sizes[1];

  char* w = (char*)d_ws;
  auto alloc = [&](size_t bytes) {
    char* p = w;
    w += (bytes + 255) & ~(size_t)255;
    return p;
  };
  int* deg_out   = (int*)alloc((size_t)NTOT * 4);
  int* deg_in    = (int*)alloc((size_t)NTOT * 4);
  int* row_start = (int*)alloc((size_t)(NTOT + 1) * 4);
  int* cursor    = (int*)alloc((size_t)NTOT * 4);
  int* bsums     = (int*)alloc(256 * 4);
  int* csr       = (int*)alloc((size_t)nE * 4);
  __bf16* h1  = (__bf16*)alloc((size_t)NTOT * HD * 2);
  __bf16* xb  = (__bf16*)alloc((size_t)NTOT * HD * 2);
  float* part = (float*)alloc((size_t)NKB * NB * FC * 4);
  float* xf   = (float*)alloc((size_t)NB * FC * 4);
  float* z    = (float*)alloc((size_t)NB * LAT * 4);
  __bf16* dbuf = h1;   // reuse (h1 dead after k_agg1)
  __bf16* dds  = xb;   // reuse (xb dead after k_gemm)

  float* out_mean   = (float*)d_out;
  float* out_logstd = (float*)d_out + 4096;
  float* out_nodes  = (float*)d_out + 8192;

  int eb = (nE + 255) / 256;
  hipMemsetAsync(deg_out, 0, 2 * (size_t)NTOT * 4, stream);  // deg_out + deg_in adjacent
  k_count<<<eb, 256, 0, stream>>>(senders, recvs, deg_out, deg_in, nE);
  k_scan1<<<NTOT / 256, 256, 0, stream>>>(deg_in, row_start, bsums);
  k_scan2<<<NTOT / 256, 256, 0, stream>>>(row_start, cursor, bsums, nE);
  k_fill<<<eb, 256, 0, stream>>>(senders, recvs, cursor, csr, nE);
  k_node1<<<NTOT / 4, 256, 0, stream>>>(nodes, W1, b1, deg_out, h1);
  k_agg1<<<NTOT / 4, 256, 0, stream>>>(h1, row_start, csr, deg_in, xb);
  k_gemm<<<NKB, 512, 0, stream>>>(xb, Wfc, part);
  k_reduce<<<NB * FC / 128, 256, 0, stream>>>(part, bfc, xf);
  k_head<<<NB, 256, 0, stream>>>(xf, Wm, bm, Wl, bl, eps, out_mean, out_logstd, z);
  k_dec_fc<<<64000 / 32, 256, 0, stream>>>(z, Wdf, bdf, dbuf);
  k_dec_out<<<NTOT / 8, 256, 0, stream>>>(dbuf, Wdo, bdo, deg_out, dds);
  k_agg2<<<NTOT / 8, 256, 0, stream>>>(dds, row_start, csr, deg_in, out_nodes);
}

// Round 4
// 284.912 us; speedup vs baseline: 1.7518x; 1.2734x over previous
//
#include <hip/hip_runtime.h>
#include <math.h>

#define NTOT 64000
#define HD   64
#define NB   64
#define FC   512
#define LAT  64
#define OUTD 32
#define GKC  256
#define NKB  250   // 64000 / GKC
#define NBH  64    // histogram privatization copies per array

typedef __bf16 bf16x8 __attribute__((ext_vector_type(8)));
typedef float  f32x4  __attribute__((ext_vector_type(4)));

__device__ inline float bflo(unsigned u) { union {unsigned q; float f;} x; x.q = u << 16; return x.f; }
__device__ inline float bfhi(unsigned u) { union {unsigned q; float f;} x; x.q = u & 0xFFFF0000u; return x.f; }
__device__ inline unsigned pkbf(float lo, float hi) {
  __bf16 a = (__bf16)lo, b = (__bf16)hi;
  unsigned short ua, ub;
  __builtin_memcpy(&ua, &a, 2); __builtin_memcpy(&ub, &b, 2);
  return (unsigned)ua | ((unsigned)ub << 16);
}

// ---------- degree histogram: privatized LDS byte-packed, no global atomics ----------
__global__ __launch_bounds__(256) void k_hist(const int* __restrict__ s,
    const int* __restrict__ r, unsigned* __restrict__ partials, int nE) {
  __shared__ unsigned hist[16000];          // 64000 byte-bins packed 4/word
  int arr = blockIdx.y;                     // 0: senders->dout, 1: receivers->din
  const int* idx = arr ? r : s;
  unsigned* base = partials + ((size_t)arr * NBH + blockIdx.x) * 16000;
  for (int u = threadIdx.x; u < 16000; u += 256) hist[u] = 0;
  __syncthreads();
  int chunk = (nE + NBH - 1) / NBH;
  int e0 = blockIdx.x * chunk;
  int e1 = min(e0 + chunk, nE);
  for (int e = e0 + threadIdx.x; e < e1; e += 256) {
    int i = idx[e];
    atomicAdd(&hist[i >> 2], 1u << ((i & 3) * 8));
  }
  __syncthreads();
  for (int u = threadIdx.x; u < 16000; u += 256) base[u] = hist[u];
}

// ---------- sum partials (packed-byte adds are exact: degree < 255) ----------
__global__ __launch_bounds__(128) void k_sum(const unsigned* __restrict__ partials,
    int* __restrict__ dout, int* __restrict__ din) {
  int t = blockIdx.x * 128 + threadIdx.x;   // word index < 16000
  unsigned a = 0, b = 0;
  for (int bk = 0; bk < NBH; bk++) {
    a += partials[(size_t)bk * 16000 + t];
    b += partials[((size_t)NBH + bk) * 16000 + t];
  }
  int4 va = make_int4(a & 255, (a >> 8) & 255, (a >> 16) & 255, a >> 24);
  int4 vb = make_int4(b & 255, (b >> 8) & 255, (b >> 16) & 255, b >> 24);
  *reinterpret_cast<int4*>(dout + t * 4) = va;
  *reinterpret_cast<int4*>(din + t * 4) = vb;
}

__global__ void k_scan1(const int* __restrict__ din, int* __restrict__ rs,
                        int* __restrict__ bsums) {
  __shared__ int sm[256];
  int i = blockIdx.x * 256 + threadIdx.x;
  int v = din[i];
  sm[threadIdx.x] = v;
  __syncthreads();
  for (int d = 1; d < 256; d <<= 1) {
    int t = (threadIdx.x >= d) ? sm[threadIdx.x - d] : 0;
    __syncthreads();
    sm[threadIdx.x] += t;
    __syncthreads();
  }
  rs[i] = sm[threadIdx.x] - v;  // local exclusive
  if (threadIdx.x == 255) bsums[blockIdx.x] = sm[255];
}

__global__ void k_scan2(int* __restrict__ rs, int* __restrict__ cur,
                        const int* __restrict__ bsums, int nE) {
  __shared__ int sm[256];
  int bid = blockIdx.x, t = threadIdx.x;
  sm[t] = (t < bid) ? bsums[t] : 0;
  __syncthreads();
  for (int d = 128; d > 0; d >>= 1) {
    if (t < d) sm[t] += sm[t + d];
    __syncthreads();
  }
  int i = bid * 256 + t;
  int v = rs[i] + sm[0];
  rs[i] = v;
  cur[i] = v;
  if (bid == 0 && t == 0) rs[NTOT] = nE;
}

__global__ void k_fill(const int* __restrict__ s, const int* __restrict__ r,
                       int* __restrict__ cur, int* __restrict__ csr, int nE) {
  int i = blockIdx.x * 256 + threadIdx.x;
  if (i < nE) {
    int pos = atomicAdd(&cur[r[i]], 1);
    csr[pos] = s[i];
  }
}

// ---------- encoder node update: h1 = relu(nodes@W1+b1) * rsqrt(deg_out+1), bf16 out ----------
__global__ __launch_bounds__(256) void k_node1(const float* __restrict__ nodes,
    const float* __restrict__ W1, const float* __restrict__ b1,
    const int* __restrict__ dout, __bf16* __restrict__ h1) {
  __shared__ float wsm[HD * HD];
  int tid = threadIdx.x;
  for (int u = tid; u < HD * HD; u += 256) wsm[u] = W1[u];
  __syncthreads();
  int node = blockIdx.x * 4 + (tid >> 6);
  int f = tid & 63;
  const float* xr = nodes + (size_t)node * HD;
  float acc = b1[f];
#pragma unroll 16
  for (int k = 0; k < HD; k++) acc = fmaf(xr[k], wsm[k * HD + f], acc);
  acc = fmaxf(acc, 0.f);
  h1[(size_t)node * HD + f] = (__bf16)(acc * rsqrtf((float)(dout[node] + 1)));
}

// ---------- aggregate 1 (with self edge), F=64 as 32 packed uints ----------
__global__ __launch_bounds__(256) void k_agg1(const unsigned* __restrict__ h1u,
    const int* __restrict__ rs, const int* __restrict__ csr,
    const int* __restrict__ din, unsigned* __restrict__ xbo) {
  int tid = threadIdx.x;
  int node = blockIdx.x * 8 + (tid >> 5);
  int f2 = tid & 31;
  int beg = rs[node], end = rs[node + 1];
  unsigned su = h1u[node * 32 + f2];
  float a0 = bflo(su), b0 = bfhi(su);
  float a1 = 0, b1 = 0, a2 = 0, b2 = 0, a3 = 0, b3 = 0;
  int e = beg;
  for (; e + 4 <= end; e += 4) {
    unsigned u0 = h1u[csr[e] * 32 + f2];
    unsigned u1 = h1u[csr[e + 1] * 32 + f2];
    unsigned u2 = h1u[csr[e + 2] * 32 + f2];
    unsigned u3 = h1u[csr[e + 3] * 32 + f2];
    a0 += bflo(u0); b0 += bfhi(u0);
    a1 += bflo(u1); b1 += bfhi(u1);
    a2 += bflo(u2); b2 += bfhi(u2);
    a3 += bflo(u3); b3 += bfhi(u3);
  }
  for (; e < end; e++) {
    unsigned u = h1u[csr[e] * 32 + f2];
    a1 += bflo(u); b1 += bfhi(u);
  }
  float sc = rsqrtf((float)(din[node] + 1));
  xbo[node * 32 + f2] = pkbf(((a0 + a1) + (a2 + a3)) * sc, ((b0 + b1) + (b2 + b3)) * sc);
}

// ---------- big GEMM (MFMA bf16): part[kb] = x[:, k0:+256] @ Wfc[k0:+256, :] ----------
__global__ __launch_bounds__(512) void k_gemm(const __bf16* __restrict__ xb,
    const float* __restrict__ Wfc, float* __restrict__ part) {
  __shared__ __align__(16) __bf16 As[64 * 264];  // 33 KB, row pad +8
  int kb = blockIdx.x;
  int k0 = kb * GKC;
  int tid = threadIdx.x;
  for (int u = tid; u < 64 * 32; u += 512) {
    int row = u >> 5, c = u & 31;
    const uint4* src = reinterpret_cast<const uint4*>(xb + (size_t)row * 64000 + k0);
    reinterpret_cast<uint4*>(&As[row * 264])[c] = src[c];
  }
  __syncthreads();
  int w = tid >> 6, lane = tid & 63;
  int cw = lane & 15, kg = lane >> 4;
  const float* Bp = Wfc + ((size_t)k0 + kg * 8) * FC + w * 64 + cw;
  f32x4 acc[4][4];
#pragma unroll
  for (int mt = 0; mt < 4; mt++)
#pragma unroll
    for (int nt = 0; nt < 4; nt++) acc[mt][nt] = (f32x4){0.f, 0.f, 0.f, 0.f};

  for (int ks = 0; ks < 8; ks++) {
    bf16x8 bfrag[4];
#pragma unroll
    for (int nt = 0; nt < 4; nt++) {
      const float* bp = Bp + (size_t)ks * 32 * FC + nt * 16;
      bf16x8 bb;
#pragma unroll
      for (int b = 0; b < 8; b++) bb[b] = (__bf16)bp[(size_t)b * FC];
      bfrag[nt] = bb;
    }
    bf16x8 afrag[4];
#pragma unroll
    for (int mt = 0; mt < 4; mt++)
      afrag[mt] = *reinterpret_cast<const bf16x8*>(
          &As[(mt * 16 + cw) * 264 + ks * 32 + kg * 8]);
#pragma unroll
    for (int mt = 0; mt < 4; mt++)
#pragma unroll
      for (int nt = 0; nt < 4; nt++)
        acc[mt][nt] = __builtin_amdgcn_mfma_f32_16x16x32_bf16(
            afrag[mt], bfrag[nt], acc[mt][nt], 0, 0, 0);
  }
#pragma unroll
  for (int mt = 0; mt < 4; mt++)
#pragma unroll
    for (int nt = 0; nt < 4; nt++) {
      int col = w * 64 + nt * 16 + cw;
#pragma unroll
      for (int j = 0; j < 4; j++) {
        int row = mt * 16 + kg * 4 + j;
        part[((size_t)kb * 64 + row) * FC + col] = acc[mt][nt][j];
      }
    }
}

// ---------- reduce partials: xf = relu(sum_kb part + bfc) ----------
__global__ __launch_bounds__(256) void k_reduce(const float* __restrict__ part,
    const float* __restrict__ bfc, float* __restrict__ xf) {
  __shared__ float sm[256];
  int t = threadIdx.x;
  int i = blockIdx.x * 128 + (t & 127);  // output index < 32768
  int half = t >> 7;
  float sv = 0.f;
  int kb0 = half * (NKB / 2);
  int kb1 = kb0 + (NKB / 2);
  for (int kb = kb0; kb < kb1; kb++) sv += part[(size_t)kb * (NB * FC) + i];
  sm[t] = sv;
  __syncthreads();
  if (half == 0)
    xf[i] = fmaxf(sm[t] + sm[t + 128] + bfc[i & (FC - 1)], 0.f);
}

// ---------- heads + reparameterization ----------
__global__ __launch_bounds__(256) void k_head(const float* __restrict__ xf,
    const float* __restrict__ Wm, const float* __restrict__ bm,
    const float* __restrict__ Wl, const float* __restrict__ bl,
    const float* __restrict__ eps, float* __restrict__ out_mean,
    float* __restrict__ out_logstd, float* __restrict__ z) {
  __shared__ float xr[FC];
  __shared__ float ps[4][LAT];
  __shared__ float zm[LAT];
  int b = blockIdx.x, t = threadIdx.x;
  for (int u = t; u < FC; u += 256) xr[u] = xf[b * FC + u];
  __syncthreads();
  int g = t >> 6;
  int l = t & 63;
  int h = g & 1;
  const float* W = (g < 2) ? Wm : Wl;
  float acc = 0.f;
  int kb = h * (FC / 2);
#pragma unroll 8
  for (int k = kb; k < kb + FC / 2; k++) acc = fmaf(xr[k], W[k * LAT + l], acc);
  ps[g][l] = acc;
  __syncthreads();
  float ls = 0.f;
  if (g == 0) {
    float m = ps[0][l] + ps[1][l] + bm[l];
    out_mean[b * 64 + l] = m;
    zm[l] = m;
  }
  if (g == 2) {
    ls = ps[2][l] + ps[3][l] + bl[l];
    out_logstd[b * 64 + l] = ls;
  }
  __syncthreads();
  if (g == 2) z[b * 64 + l] = zm[l] + expf(ls) * eps[b * 64 + l];
}

// ---------- decoder fc: d = relu(z @ Wdf + bdf), bf16 out ----------
__global__ __launch_bounds__(256) void k_dec_fc(const float* __restrict__ z,
    const float* __restrict__ Wdf, const float* __restrict__ bdf,
    __bf16* __restrict__ dbuf) {
  __shared__ float zs[NB * LAT];
  int tid = threadIdx.x;
  for (int u = tid; u < NB * LAT; u += 256) zs[u] = z[u];
  __syncthreads();
  int j = blockIdx.x * 32 + (tid & 31);
  int b0 = (tid >> 5) * 8;
  float bias = bdf[j];
  float acc[8];
#pragma unroll
  for (int i = 0; i < 8; i++) acc[i] = bias;
  for (int k = 0; k < LAT; k++) {
    float w = Wdf[(size_t)k * 64000 + j];
#pragma unroll
    for (int i = 0; i < 8; i++) acc[i] = fmaf(zs[(b0 + i) * LAT + k], w, acc[i]);
  }
#pragma unroll
  for (int i = 0; i < 8; i++)
    dbuf[(size_t)(b0 + i) * 64000 + j] = (__bf16)fmaxf(acc[i], 0.f);
}

// ---------- decoder out + pre-scale ----------
__global__ __launch_bounds__(256) void k_dec_out(const __bf16* __restrict__ dbuf,
    const float* __restrict__ Wdo, const float* __restrict__ bdo,
    const int* __restrict__ dout, __bf16* __restrict__ dds) {
  __shared__ float wsm[HD * OUTD];
  __shared__ float dr[8][HD];
  int tid = threadIdx.x;
  for (int u = tid; u < HD * OUTD; u += 256) wsm[u] = Wdo[u];
  int node0 = blockIdx.x * 8;
  {
    int nl = tid >> 5, k = tid & 31;
    dr[nl][k]      = (float)dbuf[(size_t)(node0 + nl) * HD + k];
    dr[nl][k + 32] = (float)dbuf[(size_t)(node0 + nl) * HD + k + 32];
  }
  __syncthreads();
  int nl = tid >> 5, f = tid & 31;
  int node = node0 + nl;
  float acc = bdo[f];
#pragma unroll 8
  for (int k = 0; k < HD; k++) acc = fmaf(dr[nl][k], wsm[k * OUTD + f], acc);
  dds[(size_t)node * OUTD + f] = (__bf16)(acc * rsqrtf(fmaxf((float)dout[node], 1.f)));
}

// ---------- aggregate 2 (no self edges), F=32 as 16 packed uints ----------
__global__ __launch_bounds__(256) void k_agg2(const unsigned* __restrict__ ddsu,
    const int* __restrict__ rs, const int* __restrict__ csr,
    const int* __restrict__ din, float* __restrict__ outn) {
  int tid = threadIdx.x;
  int node = blockIdx.x * 16 + (tid >> 4);
  int f2 = tid & 15;
  int beg = rs[node], end = rs[node + 1];
  float a0 = 0, b0 = 0, a1 = 0, b1 = 0, a2 = 0, b2 = 0, a3 = 0, b3 = 0;
  int e = beg;
  for (; e + 4 <= end; e += 4) {
    unsigned u0 = ddsu[csr[e] * 16 + f2];
    unsigned u1 = ddsu[csr[e + 1] * 16 + f2];
    unsigned u2 = ddsu[csr[e + 2] * 16 + f2];
    unsigned u3 = ddsu[csr[e + 3] * 16 + f2];
    a0 += bflo(u0); b0 += bfhi(u0);
    a1 += bflo(u1); b1 += bfhi(u1);
    a2 += bflo(u2); b2 += bfhi(u2);
    a3 += bflo(u3); b3 += bfhi(u3);
  }
  for (; e < end; e++) {
    unsigned u = ddsu[csr[e] * 16 + f2];
    a1 += bflo(u); b1 += bfhi(u);
  }
  float sc = rsqrtf(fmaxf((float)din[node], 1.f));
  float2 o = make_float2(((a0 + a1) + (a2 + a3)) * sc, ((b0 + b1) + (b2 + b3)) * sc);
  *reinterpret_cast<float2*>(outn + (size_t)node * 32 + f2 * 2) = o;
}

extern "C" void kernel_launch(void* const* d_in, const int* in_sizes, int n_in,
                              void* d_out, int out_size, void* d_ws, size_t ws_size,
                              hipStream_t stream) {
  const float* nodes   = (const float*)d_in[0];
  const int*   senders = (const int*)d_in[1];
  const int*   recvs   = (const int*)d_in[2];
  const float* eps     = (const float*)d_in[3];
  const float* W1      = (const float*)d_in[4];
  const float* b1      = (const float*)d_in[5];
  const float* Wfc     = (const float*)d_in[6];
  const float* bfc     = (const float*)d_in[7];
  const float* Wm      = (const float*)d_in[8];
  const float* bm      = (const float*)d_in[9];
  const float* Wl      = (const float*)d_in[10];
  const float* bl      = (const float*)d_in[11];
  const float* Wdf     = (const float*)d_in[12];
  const float* bdf     = (const float*)d_in[13];
  const float* Wdo     = (const float*)d_in[14];
  const float* bdo     = (const float*)d_in[15];
  int nE = in_sizes[1];

  char* w = (char*)d_ws;
  auto alloc = [&](size_t bytes) {
    char* p = w;
    w += (bytes + 255) & ~(size_t)255;
    return p;
  };
  int* deg_out   = (int*)alloc((size_t)NTOT * 4);
  int* deg_in    = (int*)alloc((size_t)NTOT * 4);
  int* row_start = (int*)alloc((size_t)(NTOT + 1) * 4);
  int* cursor    = (int*)alloc((size_t)NTOT * 4);
  int* bsums     = (int*)alloc(256 * 4);
  int* csr       = (int*)alloc((size_t)nE * 4);
  __bf16* h1  = (__bf16*)alloc((size_t)NTOT * HD * 2);
  __bf16* xb  = (__bf16*)alloc((size_t)NTOT * HD * 2);
  float* part = (float*)alloc((size_t)NKB * NB * FC * 4);
  float* xf   = (float*)alloc((size_t)NB * FC * 4);
  float* z    = (float*)alloc((size_t)NB * LAT * 4);
  __bf16* dbuf = h1;                    // reuse (h1 dead after k_agg1)
  __bf16* dds  = xb;                    // reuse (xb dead after k_gemm)
  unsigned* partials = (unsigned*)part; // reuse (dead before k_gemm writes part)

  float* out_mean   = (float*)d_out;
  float* out_logstd = (float*)d_out + 4096;
  float* out_nodes  = (float*)d_out + 8192;

  int eb = (nE + 255) / 256;
  k_hist<<<dim3(NBH, 2), 256, 0, stream>>>(senders, recvs, partials, nE);
  k_sum<<<125, 128, 0, stream>>>(partials, deg_out, deg_in);
  k_scan1<<<NTOT / 256, 256, 0, stream>>>(deg_in, row_start, bsums);
  k_scan2<<<NTOT / 256, 256, 0, stream>>>(row_start, cursor, bsums, nE);
  k_fill<<<eb, 256, 0, stream>>>(senders, recvs, cursor, csr, nE);
  k_node1<<<NTOT / 4, 256, 0, stream>>>(nodes, W1, b1, deg_out, h1);
  k_agg1<<<NTOT / 8, 256, 0, stream>>>((const unsigned*)h1, row_start, csr, deg_in, (unsigned*)xb);
  k_gemm<<<NKB, 512, 0, stream>>>(xb, Wfc, part);
  k_reduce<<<NB * FC / 128, 256, 0, stream>>>(part, bfc, xf);
  k_head<<<NB, 256, 0, stream>>>(xf, Wm, bm, Wl, bl, eps, out_mean, out_logstd, z);
  k_dec_fc<<<64000 / 32, 256, 0, stream>>>(z, Wdf, bdf, dbuf);
  k_dec_out<<<NTOT / 8, 256, 0, stream>>>(dbuf, Wdo, bdo, deg_out, dds);
  k_agg2<<<NTOT / 16, 256, 0, stream>>>((const unsigned*)dds, row_start, csr, deg_in, out_nodes);
}

// Round 5
// 249.818 us; speedup vs baseline: 1.9979x; 1.1405x over previous
//
#include <hip/hip_runtime.h>
#include <math.h>

#define NTOT 64000
#define HD   64
#define NB   64
#define FC   512
#define LAT  64
#define OUTD 32
#define GKC  256
#define NKB  250   // 64000 / GKC
#define NBH  64    // histogram privatization copies per array
#define NBUK 250   // CSR buckets (256 nodes each)
#define BSH  8

typedef __bf16 bf16x8 __attribute__((ext_vector_type(8)));
typedef float  f32x4  __attribute__((ext_vector_type(4)));

__device__ inline float bflo(unsigned u) { union {unsigned q; float f;} x; x.q = u << 16; return x.f; }
__device__ inline float bfhi(unsigned u) { union {unsigned q; float f;} x; x.q = u & 0xFFFF0000u; return x.f; }
__device__ inline unsigned pkbf(float lo, float hi) {
  __bf16 a = (__bf16)lo, b = (__bf16)hi;
  unsigned short ua, ub;
  __builtin_memcpy(&ua, &a, 2); __builtin_memcpy(&ub, &b, 2);
  return (unsigned)ua | ((unsigned)ub << 16);
}

// ---------- degree histogram: privatized LDS byte-packed, no global atomics ----------
__global__ __launch_bounds__(256) void k_hist(const int* __restrict__ s,
    const int* __restrict__ r, unsigned* __restrict__ partials, int nE) {
  __shared__ unsigned hist[16000];          // 64000 byte-bins packed 4/word
  int arr = blockIdx.y;                     // 0: senders->dout, 1: receivers->din
  const int* idx = arr ? r : s;
  unsigned* base = partials + ((size_t)arr * NBH + blockIdx.x) * 16000;
  for (int u = threadIdx.x; u < 16000; u += 256) hist[u] = 0;
  __syncthreads();
  int chunk = (nE + NBH - 1) / NBH;
  int e0 = blockIdx.x * chunk;
  int e1 = min(e0 + chunk, nE);
  for (int e = e0 + threadIdx.x; e < e1; e += 256) {
    int i = idx[e];
    atomicAdd(&hist[i >> 2], 1u << ((i & 3) * 8));
  }
  __syncthreads();
  for (int u = threadIdx.x; u < 16000; u += 256) base[u] = hist[u];
}

// ---------- sum partials (packed-byte adds are exact: degree < 255) ----------
__global__ __launch_bounds__(128) void k_sum(const unsigned* __restrict__ partials,
    int* __restrict__ dout, int* __restrict__ din) {
  int t = blockIdx.x * 128 + threadIdx.x;   // word index < 16000
  unsigned a = 0, b = 0;
  for (int bk = 0; bk < NBH; bk++) {
    a += partials[(size_t)bk * 16000 + t];
    b += partials[((size_t)NBH + bk) * 16000 + t];
  }
  int4 va = make_int4(a & 255, (a >> 8) & 255, (a >> 16) & 255, a >> 24);
  int4 vb = make_int4(b & 255, (b >> 8) & 255, (b >> 16) & 255, b >> 24);
  *reinterpret_cast<int4*>(dout + t * 4) = va;
  *reinterpret_cast<int4*>(din + t * 4) = vb;
}

__global__ void k_scan1(const int* __restrict__ din, int* __restrict__ rs,
                        int* __restrict__ bsums) {
  __shared__ int sm[256];
  int i = blockIdx.x * 256 + threadIdx.x;
  int v = din[i];
  sm[threadIdx.x] = v;
  __syncthreads();
  for (int d = 1; d < 256; d <<= 1) {
    int t = (threadIdx.x >= d) ? sm[threadIdx.x - d] : 0;
    __syncthreads();
    sm[threadIdx.x] += t;
    __syncthreads();
  }
  rs[i] = sm[threadIdx.x] - v;  // local exclusive
  if (threadIdx.x == 255) bsums[blockIdx.x] = sm[255];
}

__global__ void k_scan2(int* __restrict__ rs, int* __restrict__ gcur,
                        const int* __restrict__ bsums, int nE) {
  __shared__ int sm[256];
  int bid = blockIdx.x, t = threadIdx.x;
  sm[t] = (t < bid) ? bsums[t] : 0;
  __syncthreads();
  for (int d = 128; d > 0; d >>= 1) {
    if (t < d) sm[t] += sm[t + d];
    __syncthreads();
  }
  int i = bid * 256 + t;
  int v = rs[i] + sm[0];
  rs[i] = v;
  if ((i & 255) == 0) gcur[i >> 8] = v;   // bucket base (exclusive prefix)
  if (bid == 0 && t == 0) rs[NTOT] = nE;
}

// ---------- CSR build phase A: bucket edges (packed) into ebuf ----------
__global__ __launch_bounds__(256) void k_bucket(const int* __restrict__ s,
    const int* __restrict__ r, int* __restrict__ gcur,
    unsigned* __restrict__ ebuf, int nE) {
  __shared__ int cnt[NBUK];
  __shared__ int base[NBUK];
  int tid = threadIdx.x;
  int chunk = (nE + gridDim.x - 1) / gridDim.x;
  int e0 = blockIdx.x * chunk;
  int e1 = min(e0 + chunk, nE);
  for (int u = tid; u < NBUK; u += 256) cnt[u] = 0;
  __syncthreads();
  for (int e = e0 + tid; e < e1; e += 256)
    atomicAdd(&cnt[r[e] >> BSH], 1);
  __syncthreads();
  for (int u = tid; u < NBUK; u += 256) {
    base[u] = atomicAdd(&gcur[u], cnt[u]);
    cnt[u] = 0;
  }
  __syncthreads();
  for (int e = e0 + tid; e < e1; e += 256) {
    int rr = r[e];
    int b = rr >> BSH;
    int off = atomicAdd(&cnt[b], 1);
    ebuf[base[b] + off] = ((unsigned)(rr & 255) << 16) | (unsigned)s[e];
  }
}

// ---------- CSR build phase B: per-bucket local fill (cache-local scatter) ----------
__global__ __launch_bounds__(256) void k_fill2(const unsigned* __restrict__ ebuf,
    const int* __restrict__ rs, int* __restrict__ csr) {
  __shared__ int cur[256];
  int b = blockIdx.x;
  int tid = threadIdx.x;
  int nbase = b << BSH;
  cur[tid] = rs[nbase + tid];
  __syncthreads();
  int e0 = rs[nbase];
  int e1 = rs[nbase + 256];   // b=249: rs[64000] = nE
  for (int e = e0 + tid; e < e1; e += 256) {
    unsigned p = ebuf[e];
    int pos = atomicAdd(&cur[p >> 16], 1);
    csr[pos] = (int)(p & 0xFFFFu);
  }
}

// ---------- encoder node update: h1 = relu(nodes@W1+b1) * rsqrt(deg_out+1), bf16 out ----------
__global__ __launch_bounds__(256) void k_node1(const float* __restrict__ nodes,
    const float* __restrict__ W1, const float* __restrict__ b1,
    const int* __restrict__ dout, __bf16* __restrict__ h1) {
  __shared__ float wsm[HD * HD];
  int tid = threadIdx.x;
  for (int u = tid; u < HD * HD; u += 256) wsm[u] = W1[u];
  __syncthreads();
  int node = blockIdx.x * 4 + (tid >> 6);
  int f = tid & 63;
  const float* xr = nodes + (size_t)node * HD;
  float acc = b1[f];
#pragma unroll 16
  for (int k = 0; k < HD; k++) acc = fmaf(xr[k], wsm[k * HD + f], acc);
  acc = fmaxf(acc, 0.f);
  h1[(size_t)node * HD + f] = (__bf16)(acc * rsqrtf((float)(dout[node] + 1)));
}

// ---------- aggregate 1 (with self edge), F=64 as 32 packed uints ----------
__global__ __launch_bounds__(256) void k_agg1(const unsigned* __restrict__ h1u,
    const int* __restrict__ rs, const int* __restrict__ csr,
    const int* __restrict__ din, unsigned* __restrict__ xbo) {
  int tid = threadIdx.x;
  int node = blockIdx.x * 8 + (tid >> 5);
  int f2 = tid & 31;
  int beg = rs[node], end = rs[node + 1];
  unsigned su = h1u[node * 32 + f2];
  float a0 = bflo(su), b0 = bfhi(su);
  float a1 = 0, b1 = 0, a2 = 0, b2 = 0, a3 = 0, b3 = 0;
  int e = beg;
  for (; e + 4 <= end; e += 4) {
    unsigned u0 = h1u[csr[e] * 32 + f2];
    unsigned u1 = h1u[csr[e + 1] * 32 + f2];
    unsigned u2 = h1u[csr[e + 2] * 32 + f2];
    unsigned u3 = h1u[csr[e + 3] * 32 + f2];
    a0 += bflo(u0); b0 += bfhi(u0);
    a1 += bflo(u1); b1 += bfhi(u1);
    a2 += bflo(u2); b2 += bfhi(u2);
    a3 += bflo(u3); b3 += bfhi(u3);
  }
  for (; e < end; e++) {
    unsigned u = h1u[csr[e] * 32 + f2];
    a1 += bflo(u); b1 += bfhi(u);
  }
  float sc = rsqrtf((float)(din[node] + 1));
  xbo[node * 32 + f2] = pkbf(((a0 + a1) + (a2 + a3)) * sc, ((b0 + b1) + (b2 + b3)) * sc);
}

// ---------- big GEMM (MFMA bf16): part[kb] = x[:, k0:+256] @ Wfc[k0:+256, :] ----------
__global__ __launch_bounds__(512) void k_gemm(const __bf16* __restrict__ xb,
    const float* __restrict__ Wfc, float* __restrict__ part) {
  __shared__ __align__(16) __bf16 As[64 * 264];  // 33 KB, row pad +8
  int kb = blockIdx.x;
  int k0 = kb * GKC;
  int tid = threadIdx.x;
  for (int u = tid; u < 64 * 32; u += 512) {
    int row = u >> 5, c = u & 31;
    const uint4* src = reinterpret_cast<const uint4*>(xb + (size_t)row * 64000 + k0);
    reinterpret_cast<uint4*>(&As[row * 264])[c] = src[c];
  }
  __syncthreads();
  int w = tid >> 6, lane = tid & 63;
  int cw = lane & 15, kg = lane >> 4;
  const float* Bp = Wfc + ((size_t)k0 + kg * 8) * FC + w * 64 + cw;
  f32x4 acc[4][4];
#pragma unroll
  for (int mt = 0; mt < 4; mt++)
#pragma unroll
    for (int nt = 0; nt < 4; nt++) acc[mt][nt] = (f32x4){0.f, 0.f, 0.f, 0.f};

  for (int ks = 0; ks < 8; ks++) {
    bf16x8 bfrag[4];
#pragma unroll
    for (int nt = 0; nt < 4; nt++) {
      const float* bp = Bp + (size_t)ks * 32 * FC + nt * 16;
      bf16x8 bb;
#pragma unroll
      for (int b = 0; b < 8; b++) bb[b] = (__bf16)bp[(size_t)b * FC];
      bfrag[nt] = bb;
    }
    bf16x8 afrag[4];
#pragma unroll
    for (int mt = 0; mt < 4; mt++)
      afrag[mt] = *reinterpret_cast<const bf16x8*>(
          &As[(mt * 16 + cw) * 264 + ks * 32 + kg * 8]);
#pragma unroll
    for (int mt = 0; mt < 4; mt++)
#pragma unroll
      for (int nt = 0; nt < 4; nt++)
        acc[mt][nt] = __builtin_amdgcn_mfma_f32_16x16x32_bf16(
            afrag[mt], bfrag[nt], acc[mt][nt], 0, 0, 0);
  }
#pragma unroll
  for (int mt = 0; mt < 4; mt++)
#pragma unroll
    for (int nt = 0; nt < 4; nt++) {
      int col = w * 64 + nt * 16 + cw;
#pragma unroll
      for (int j = 0; j < 4; j++) {
        int row = mt * 16 + kg * 4 + j;
        part[((size_t)kb * 64 + row) * FC + col] = acc[mt][nt][j];
      }
    }
}

// ---------- reduce partials: xf = relu(sum_kb part + bfc) ----------
__global__ __launch_bounds__(256) void k_reduce(const float* __restrict__ part,
    const float* __restrict__ bfc, float* __restrict__ xf) {
  __shared__ float sm[256];
  int t = threadIdx.x;
  int i = blockIdx.x * 128 + (t & 127);  // output index < 32768
  int half = t >> 7;
  float sv = 0.f;
  int kb0 = half * (NKB / 2);
  int kb1 = kb0 + (NKB / 2);
  for (int kb = kb0; kb < kb1; kb++) sv += part[(size_t)kb * (NB * FC) + i];
  sm[t] = sv;
  __syncthreads();
  if (half == 0)
    xf[i] = fmaxf(sm[t] + sm[t + 128] + bfc[i & (FC - 1)], 0.f);
}

// ---------- heads + reparameterization ----------
__global__ __launch_bounds__(256) void k_head(const float* __restrict__ xf,
    const float* __restrict__ Wm, const float* __restrict__ bm,
    const float* __restrict__ Wl, const float* __restrict__ bl,
    const float* __restrict__ eps, float* __restrict__ out_mean,
    float* __restrict__ out_logstd, float* __restrict__ z) {
  __shared__ float xr[FC];
  __shared__ float ps[4][LAT];
  __shared__ float zm[LAT];
  int b = blockIdx.x, t = threadIdx.x;
  for (int u = t; u < FC; u += 256) xr[u] = xf[b * FC + u];
  __syncthreads();
  int g = t >> 6;
  int l = t & 63;
  int h = g & 1;
  const float* W = (g < 2) ? Wm : Wl;
  float acc = 0.f;
  int kb = h * (FC / 2);
#pragma unroll 8
  for (int k = kb; k < kb + FC / 2; k++) acc = fmaf(xr[k], W[k * LAT + l], acc);
  ps[g][l] = acc;
  __syncthreads();
  float ls = 0.f;
  if (g == 0) {
    float m = ps[0][l] + ps[1][l] + bm[l];
    out_mean[b * 64 + l] = m;
    zm[l] = m;
  }
  if (g == 2) {
    ls = ps[2][l] + ps[3][l] + bl[l];
    out_logstd[b * 64 + l] = ls;
  }
  __syncthreads();
  if (g == 2) z[b * 64 + l] = zm[l] + expf(ls) * eps[b * 64 + l];
}

// ---------- decoder fc: d = relu(z @ Wdf + bdf), bf16 out ----------
__global__ __launch_bounds__(256) void k_dec_fc(const float* __restrict__ z,
    const float* __restrict__ Wdf, const float* __restrict__ bdf,
    __bf16* __restrict__ dbuf) {
  __shared__ float zs[NB * LAT];
  int tid = threadIdx.x;
  for (int u = tid; u < NB * LAT; u += 256) zs[u] = z[u];
  __syncthreads();
  int j = blockIdx.x * 32 + (tid & 31);
  int b0 = (tid >> 5) * 8;
  float bias = bdf[j];
  float acc[8];
#pragma unroll
  for (int i = 0; i < 8; i++) acc[i] = bias;
  for (int k = 0; k < LAT; k++) {
    float w = Wdf[(size_t)k * 64000 + j];
#pragma unroll
    for (int i = 0; i < 8; i++) acc[i] = fmaf(zs[(b0 + i) * LAT + k], w, acc[i]);
  }
#pragma unroll
  for (int i = 0; i < 8; i++)
    dbuf[(size_t)(b0 + i) * 64000 + j] = (__bf16)fmaxf(acc[i], 0.f);
}

// ---------- decoder out + pre-scale ----------
__global__ __launch_bounds__(256) void k_dec_out(const __bf16* __restrict__ dbuf,
    const float* __restrict__ Wdo, const float* __restrict__ bdo,
    const int* __restrict__ dout, __bf16* __restrict__ dds) {
  __shared__ float wsm[HD * OUTD];
  __shared__ float dr[8][HD];
  int tid = threadIdx.x;
  for (int u = tid; u < HD * OUTD; u += 256) wsm[u] = Wdo[u];
  int node0 = blockIdx.x * 8;
  {
    int nl = tid >> 5, k = tid & 31;
    dr[nl][k]      = (float)dbuf[(size_t)(node0 + nl) * HD + k];
    dr[nl][k + 32] = (float)dbuf[(size_t)(node0 + nl) * HD + k + 32];
  }
  __syncthreads();
  int nl = tid >> 5, f = tid & 31;
  int node = node0 + nl;
  float acc = bdo[f];
#pragma unroll 8
  for (int k = 0; k < HD; k++) acc = fmaf(dr[nl][k], wsm[k * OUTD + f], acc);
  dds[(size_t)node * OUTD + f] = (__bf16)(acc * rsqrtf(fmaxf((float)dout[node], 1.f)));
}

// ---------- aggregate 2 (no self edges), F=32 as 16 packed uints ----------
__global__ __launch_bounds__(256) void k_agg2(const unsigned* __restrict__ ddsu,
    const int* __restrict__ rs, const int* __restrict__ csr,
    const int* __restrict__ din, float* __restrict__ outn) {
  int tid = threadIdx.x;
  int node = blockIdx.x * 16 + (tid >> 4);
  int f2 = tid & 15;
  int beg = rs[node], end = rs[node + 1];
  float a0 = 0, b0 = 0, a1 = 0, b1 = 0, a2 = 0, b2 = 0, a3 = 0, b3 = 0;
  int e = beg;
  for (; e + 4 <= end; e += 4) {
    unsigned u0 = ddsu[csr[e] * 16 + f2];
    unsigned u1 = ddsu[csr[e + 1] * 16 + f2];
    unsigned u2 = ddsu[csr[e + 2] * 16 + f2];
    unsigned u3 = ddsu[csr[e + 3] * 16 + f2];
    a0 += bflo(u0); b0 += bfhi(u0);
    a1 += bflo(u1); b1 += bfhi(u1);
    a2 += bflo(u2); b2 += bfhi(u2);
    a3 += bflo(u3); b3 += bfhi(u3);
  }
  for (; e < end; e++) {
    unsigned u = ddsu[csr[e] * 16 + f2];
    a1 += bflo(u); b1 += bfhi(u);
  }
  float sc = rsqrtf(fmaxf((float)din[node], 1.f));
  float2 o = make_float2(((a0 + a1) + (a2 + a3)) * sc, ((b0 + b1) + (b2 + b3)) * sc);
  *reinterpret_cast<float2*>(outn + (size_t)node * 32 + f2 * 2) = o;
}

extern "C" void kernel_launch(void* const* d_in, const int* in_sizes, int n_in,
                              void* d_out, int out_size, void* d_ws, size_t ws_size,
                              hipStream_t stream) {
  const float* nodes   = (const float*)d_in[0];
  const int*   senders = (const int*)d_in[1];
  const int*   recvs   = (const int*)d_in[2];
  const float* eps     = (const float*)d_in[3];
  const float* W1      = (const float*)d_in[4];
  const float* b1      = (const float*)d_in[5];
  const float* Wfc     = (const float*)d_in[6];
  const float* bfc     = (const float*)d_in[7];
  const float* Wm      = (const float*)d_in[8];
  const float* bm      = (const float*)d_in[9];
  const float* Wl      = (const float*)d_in[10];
  const float* bl      = (const float*)d_in[11];
  const float* Wdf     = (const float*)d_in[12];
  const float* bdf     = (const float*)d_in[13];
  const float* Wdo     = (const float*)d_in[14];
  const float* bdo     = (const float*)d_in[15];
  int nE = in_sizes[1];

  char* w = (char*)d_ws;
  auto alloc = [&](size_t bytes) {
    char* p = w;
    w += (bytes + 255) & ~(size_t)255;
    return p;
  };
  int* deg_out   = (int*)alloc((size_t)NTOT * 4);
  int* deg_in    = (int*)alloc((size_t)NTOT * 4);
  int* row_start = (int*)alloc((size_t)(NTOT + 1) * 4);
  int* gcur      = (int*)alloc((size_t)NBUK * 4);
  int* bsums     = (int*)alloc(256 * 4);
  int* csr       = (int*)alloc((size_t)nE * 4);
  unsigned* ebuf = (unsigned*)alloc((size_t)nE * 4);
  __bf16* h1  = (__bf16*)alloc((size_t)NTOT * HD * 2);
  __bf16* xb  = (__bf16*)alloc((size_t)NTOT * HD * 2);
  float* part = (float*)alloc((size_t)NKB * NB * FC * 4);
  float* xf   = (float*)alloc((size_t)NB * FC * 4);
  float* z    = (float*)alloc((size_t)NB * LAT * 4);
  __bf16* dbuf = h1;                    // reuse (h1 dead after k_agg1)
  __bf16* dds  = xb;                    // reuse (xb dead after k_gemm)
  unsigned* partials = (unsigned*)part; // reuse (dead before k_gemm writes part)

  float* out_mean   = (float*)d_out;
  float* out_logstd = (float*)d_out + 4096;
  float* out_nodes  = (float*)d_out + 8192;

  k_hist<<<dim3(NBH, 2), 256, 0, stream>>>(senders, recvs, partials, nE);
  k_sum<<<125, 128, 0, stream>>>(partials, deg_out, deg_in);
  k_scan1<<<NTOT / 256, 256, 0, stream>>>(deg_in, row_start, bsums);
  k_scan2<<<NTOT / 256, 256, 0, stream>>>(row_start, gcur, bsums, nE);
  k_bucket<<<256, 256, 0, stream>>>(senders, recvs, gcur, ebuf, nE);
  k_fill2<<<NBUK, 256, 0, stream>>>(ebuf, row_start, csr);
  k_node1<<<NTOT / 4, 256, 0, stream>>>(nodes, W1, b1, deg_out, h1);
  k_agg1<<<NTOT / 8, 256, 0, stream>>>((const unsigned*)h1, row_start, csr, deg_in, (unsigned*)xb);
  k_gemm<<<NKB, 512, 0, stream>>>(xb, Wfc, part);
  k_reduce<<<NB * FC / 128, 256, 0, stream>>>(part, bfc, xf);
  k_head<<<NB, 256, 0, stream>>>(xf, Wm, bm, Wl, bl, eps, out_mean, out_logstd, z);
  k_dec_fc<<<64000 / 32, 256, 0, stream>>>(z, Wdf, bdf, dbuf);
  k_dec_out<<<NTOT / 8, 256, 0, stream>>>(dbuf, Wdo, bdo, deg_out, dds);
  k_agg2<<<NTOT / 16, 256, 0, stream>>>((const unsigned*)dds, row_start, csr, deg_in, out_nodes);
}